// Round 5
// baseline (307.300 us; speedup 1.0000x reference)
//
#include <hip/hip_runtime.h>

// GeodesicAttentionBlock fused kernel, fp32 inputs -> fp32 output, MI355X gfx950.
// R5: occupancy-focused restructure. LDS 126KB -> 75.8KB (2 blocks/CU, 16 waves),
// sqs buffer + softmax phase deleted (in-lane softmax from sq-GEMM epilogue via
// wave-private f16 logit buffer), residual moved to coalesced LN phase,
// __launch_bounds__(512,4) to pin VGPR<=128 for 4 waves/SIMD.

typedef __bf16 bf16x8 __attribute__((ext_vector_type(8)));
typedef _Float16 f16x8 __attribute__((ext_vector_type(8)));
typedef float  f32x4  __attribute__((ext_vector_type(4)));
typedef int    i32x4  __attribute__((ext_vector_type(4)));
typedef int    i32x2  __attribute__((ext_vector_type(2)));
typedef unsigned short u16;

__device__ __forceinline__ float bf2f(u16 u){
  unsigned int x = ((unsigned int)u) << 16;
  return __builtin_bit_cast(float, x);
}
__device__ __forceinline__ u16 f2bf(float f){
  unsigned int u = __builtin_bit_cast(unsigned int, f);
  u += 0x7FFFu + ((u >> 16) & 1u);          // round-to-nearest-even
  return (u16)(u >> 16);
}
__device__ __forceinline__ unsigned int pk2(float lo, float hi){
  return ((unsigned int)f2bf(hi) << 16) | (unsigned int)f2bf(lo);
}
__device__ __forceinline__ bf16x8 ldfrag(const u16* p){
  return __builtin_bit_cast(bf16x8, *(const i32x4*)p);
}

#define LROW 264   // padded bf16 LDS row (256+8): 16B-aligned rows

// ---------------- prep: build Wd, WvT, WoutT (bf16) in workspace ----------------
// ws layout (u16 elems): Wd [2048][256] @0 ; WvT [256][256] @524288 ; WoutT @589824
__global__ __launch_bounds__(256) void geo_prep(
    const float* __restrict__ Wq, const float* __restrict__ Wk,
    const float* __restrict__ Wv, const float* __restrict__ Wout,
    const float* __restrict__ L, u16* __restrict__ ws)
{
  u16* Wd    = ws;
  u16* WvT   = ws + 524288;
  u16* WoutT = ws + 589824;
  const int b = blockIdx.x, t = threadIdx.x;

  if (b < 64){
    // block (q,k): Wd[(q*256 + k*32 + f)][c] = sum_d (Wq[c][q*32+d]-Wk[c][k*32+d]) * L[k][d][f]
    const int q = b >> 3, k = b & 7;
    __shared__ float dwb[256][33];
    __shared__ float Lk[32][33];
    for (int i = 0; i < 4; ++i){
      int idx = t + i*256;
      Lk[idx >> 5][idx & 31] = L[k*1024 + idx];
    }
    {
      const int c = t;
      const float* wqp = Wq + c*256 + q*32;
      const float* wkp = Wk + c*256 + k*32;
      #pragma unroll
      for (int j = 0; j < 8; ++j){
        f32x4 a  = *(const f32x4*)(wqp + j*4);
        f32x4 bb = *(const f32x4*)(wkp + j*4);
        #pragma unroll
        for (int p = 0; p < 4; ++p) dwb[c][j*4 + p] = a[p] - bb[p];
      }
    }
    __syncthreads();
    const int c = t;
    float wreg[32];
    #pragma unroll
    for (int d = 0; d < 32; ++d) wreg[d] = dwb[c][d];
    for (int f = 0; f < 32; ++f){
      float s = 0.f;
      #pragma unroll
      for (int d = 0; d < 32; ++d) s = fmaf(wreg[d], Lk[d][f], s);
      Wd[(size_t)(q*256 + k*32 + f)*256 + c] = f2bf(s);
    }
  } else {
    // transpose Wv / Wout into bf16 [n][c] layout, 64x64 tiles
    const int bb  = b - 64;
    const float* src = (bb < 16) ? Wv  : Wout;
    u16*         dst = (bb < 16) ? WvT : WoutT;
    const int tile = bb & 15;
    const int tr = tile >> 2, tc = tile & 3;
    __shared__ float tlf[64][68];
    {
      const int row = t >> 2, cs = (t & 3)*16;
      #pragma unroll
      for (int j = 0; j < 4; ++j){
        f32x4 v = *(const f32x4*)(src + (size_t)(tr*64 + row)*256 + tc*64 + cs + j*4);
        #pragma unroll
        for (int p = 0; p < 4; ++p) tlf[row][cs + j*4 + p] = v[p];
      }
    }
    __syncthreads();
    {
      const int n = t >> 2, cs = (t & 3)*16;
      float us[16];
      #pragma unroll
      for (int j = 0; j < 16; ++j) us[j] = tlf[cs + j][n];
      #pragma unroll
      for (int h = 0; h < 2; ++h){
        i32x4 o;
        #pragma unroll
        for (int p = 0; p < 4; ++p)
          o[p] = (int)pk2(us[h*8 + 2*p], us[h*8 + 2*p + 1]);
        *(i32x4*)(dst + (size_t)(tc*64 + n)*256 + tr*64 + cs + h*8) = o;
      }
    }
  }
}

// ---------------- main fused kernel ----------------
// LDS (75776 B total -> 2 blocks/CU):
//   region A @0     (33792): xs bf16[64][264]  -> ao bf16[64][264] after barrier(1)
//   region B @33792 (33792): Vs bf16[64][264]  -> hs bf16[64][256] after barrier(2)
//   region C @67584 (8192):  sqh f16[8w][64r][8k]  (wave-private logits)
__global__ __launch_bounds__(512, 4) void geo_fused(
    const float* __restrict__ x,   const u16* __restrict__ Wd,
    const u16* __restrict__ WvT,   const u16* __restrict__ WoutT,
    const float* __restrict__ b_out, const float* __restrict__ gamma,
    const float* __restrict__ beta,  float* __restrict__ out)
{
  __shared__ __align__(16) char pool[75776];
  u16  (*xs)[LROW] = (u16 (*)[LROW])(pool);
  u16  (*Vs)[LROW] = (u16 (*)[LROW])(pool + 33792);
  u16  (*ao)[LROW] = (u16 (*)[LROW])(pool);           // overlays xs
  u16  (*hs)[256]  = (u16 (*)[256])(pool + 33792);    // overlays Vs
  _Float16* sqh    = (_Float16*)(pool + 67584);

  const int t    = threadIdx.x;
  const int lane = t & 63;
  const int w    = t >> 6;           // wave 0..7 == q-head
  const int l15  = lane & 15;
  const int quad = lane >> 4;
  const long rowbase = (long)blockIdx.x * 64;

  // ---- stage x tile: fp32 loads, RNE pack to bf16 LDS ----
  {
    const int r  = t >> 3;
    const int c0 = (t & 7) * 32;
    const float* src = x + (rowbase + r)*256 + c0;
    unsigned int words[16];
    #pragma unroll
    for (int j = 0; j < 8; ++j){
      f32x4 v = *(const f32x4*)(src + j*4);
      words[j*2    ] = pk2(v[0], v[1]);
      words[j*2 + 1] = pk2(v[2], v[3]);
    }
    #pragma unroll
    for (int qd = 0; qd < 4; ++qd){
      i32x4 o;
      #pragma unroll
      for (int p = 0; p < 4; ++p) o[p] = (int)words[qd*4 + p];
      *(i32x4*)&xs[r][c0 + qd*8] = o;
    }
  }
  __syncthreads();   // barrier(0)

  // ---- V = x @ Wv : wave w covers cols [32w, 32w+32) ----
  {
    f32x4 acc[4][2];
    #pragma unroll
    for (int mt = 0; mt < 4; ++mt)
      #pragma unroll
      for (int nt = 0; nt < 2; ++nt) acc[mt][nt] = f32x4{0.f,0.f,0.f,0.f};
    #pragma unroll
    for (int kk = 0; kk < 8; ++kk){
      const int c0 = kk*32 + quad*8;
      bf16x8 a[4], bfr[2];
      #pragma unroll
      for (int mt = 0; mt < 4; ++mt) a[mt] = ldfrag(&xs[mt*16 + l15][c0]);
      #pragma unroll
      for (int nt = 0; nt < 2; ++nt){
        const int n = w*32 + nt*16 + l15;
        bfr[nt] = __builtin_bit_cast(bf16x8, *(const i32x4*)(WvT + (size_t)n*256 + c0));
      }
      #pragma unroll
      for (int mt = 0; mt < 4; ++mt)
        #pragma unroll
        for (int nt = 0; nt < 2; ++nt)
          acc[mt][nt] = __builtin_amdgcn_mfma_f32_16x16x32_bf16(a[mt], bfr[nt], acc[mt][nt], 0, 0, 0);
    }
    #pragma unroll
    for (int mt = 0; mt < 4; ++mt)
      #pragma unroll
      for (int nt = 0; nt < 2; ++nt){
        const int col = w*32 + nt*16 + l15;
        #pragma unroll
        for (int reg = 0; reg < 4; ++reg)
          Vs[mt*16 + quad*4 + reg][col] = f2bf(acc[mt][nt][reg]);
      }
  }

  // ---- sq_dist GEMM: D = Wd @ x^T; logits straight to wave-private f16 ----
  {
    #pragma unroll
    for (int kp = 0; kp < 4; ++kp){
      f32x4 acc[2][2][4];   // [k2][mt(f-half)][nt(row-tile)]
      #pragma unroll
      for (int k2 = 0; k2 < 2; ++k2)
        #pragma unroll
        for (int mt = 0; mt < 2; ++mt)
          #pragma unroll
          for (int nt = 0; nt < 4; ++nt) acc[k2][mt][nt] = f32x4{0.f,0.f,0.f,0.f};
      #pragma unroll
      for (int kk = 0; kk < 8; ++kk){
        const int c0 = kk*32 + quad*8;
        bf16x8 bfr[4];
        #pragma unroll
        for (int nt = 0; nt < 4; ++nt) bfr[nt] = ldfrag(&xs[nt*16 + l15][c0]);
        bf16x8 a[2][2];
        #pragma unroll
        for (int k2 = 0; k2 < 2; ++k2)
          #pragma unroll
          for (int mt = 0; mt < 2; ++mt){
            const int m = w*256 + (kp*2 + k2)*32 + mt*16 + l15;
            a[k2][mt] = __builtin_bit_cast(bf16x8, *(const i32x4*)(Wd + (size_t)m*256 + c0));
          }
        #pragma unroll
        for (int k2 = 0; k2 < 2; ++k2)
          #pragma unroll
          for (int mt = 0; mt < 2; ++mt)
            #pragma unroll
            for (int nt = 0; nt < 4; ++nt)
              acc[k2][mt][nt] = __builtin_amdgcn_mfma_f32_16x16x32_bf16(a[k2][mt], bfr[nt], acc[k2][mt][nt], 0, 0, 0);
      }
      #pragma unroll
      for (int k2 = 0; k2 < 2; ++k2){
        const int k = kp*2 + k2;
        #pragma unroll
        for (int nt = 0; nt < 4; ++nt){
          float s = 0.f;
          #pragma unroll
          for (int mt = 0; mt < 2; ++mt)
            #pragma unroll
            for (int reg = 0; reg < 4; ++reg){
              float d = acc[k2][mt][nt][reg];   // f = mt*16 + quad*4 + reg
              s = fmaf(d, d, s);
            }
          s += __shfl_xor(s, 16);
          s += __shfl_xor(s, 32);               // all lanes now hold sum over 32 f
          if (quad == 0)
            sqh[w*512 + (nt*16 + l15)*8 + k] =
                (_Float16)(s * -0.17677669529663687f);   // logit = -sq/sqrt(32)
        }
      }
    }
  }
  __syncthreads();   // barrier(1): xs dead, Vs complete

  // ---- in-lane softmax + attn @ V -> ao (overlays xs) ----
  {
    #pragma unroll
    for (int nt = 0; nt < 4; ++nt){
      const int r = nt*16 + l15;
      f16x8 lgh = __builtin_bit_cast(f16x8, *(const i32x4*)&sqh[w*512 + r*8]);
      float lg[8];
      #pragma unroll
      for (int k = 0; k < 8; ++k) lg[k] = (float)lgh[k];
      float mx = lg[0];
      #pragma unroll
      for (int k = 1; k < 8; ++k) mx = fmaxf(mx, lg[k]);
      float e[8], sum = 0.f;
      #pragma unroll
      for (int k = 0; k < 8; ++k){ e[k] = __expf(lg[k] - mx); sum += e[k]; }
      const float inv = 1.0f / sum;
      float o[8] = {0.f,0.f,0.f,0.f,0.f,0.f,0.f,0.f};
      #pragma unroll
      for (int k = 0; k < 8; ++k){
        i32x4 v = *(const i32x4*)&Vs[r][k*32 + quad*8];
        const float a = e[k] * inv;
        #pragma unroll
        for (int p = 0; p < 4; ++p){
          unsigned int u = (unsigned int)v[p];
          o[2*p    ] = fmaf(a, __builtin_bit_cast(float, u << 16),          o[2*p    ]);
          o[2*p + 1] = fmaf(a, __builtin_bit_cast(float, u & 0xFFFF0000u),  o[2*p + 1]);
        }
      }
      i32x4 pkv;
      #pragma unroll
      for (int p = 0; p < 4; ++p) pkv[p] = (int)pk2(o[2*p], o[2*p + 1]);
      *(i32x4*)&ao[r][w*32 + quad*8] = pkv;    // ao@xs region: safe post-barrier(1)
    }
  }
  __syncthreads();   // barrier(2): ao complete, Vs dead

  // ---- h' = ao @ Wout + b_out -> hs bf16 (overlays Vs); residual added in LN ----
  {
    f32x4 acc[4][2];
    #pragma unroll
    for (int mt = 0; mt < 4; ++mt)
      #pragma unroll
      for (int nt = 0; nt < 2; ++nt) acc[mt][nt] = f32x4{0.f,0.f,0.f,0.f};
    #pragma unroll
    for (int kk = 0; kk < 8; ++kk){
      const int c0 = kk*32 + quad*8;
      bf16x8 a[4], bfr[2];
      #pragma unroll
      for (int mt = 0; mt < 4; ++mt) a[mt] = ldfrag(&ao[mt*16 + l15][c0]);
      #pragma unroll
      for (int nt = 0; nt < 2; ++nt){
        const int n = w*32 + nt*16 + l15;
        bfr[nt] = __builtin_bit_cast(bf16x8, *(const i32x4*)(WoutT + (size_t)n*256 + c0));
      }
      #pragma unroll
      for (int mt = 0; mt < 4; ++mt)
        #pragma unroll
        for (int nt = 0; nt < 2; ++nt)
          acc[mt][nt] = __builtin_amdgcn_mfma_f32_16x16x32_bf16(a[mt], bfr[nt], acc[mt][nt], 0, 0, 0);
    }
    #pragma unroll
    for (int nt = 0; nt < 2; ++nt){
      const int col = w*32 + nt*16 + l15;
      const float bo = b_out[col];
      #pragma unroll
      for (int mt = 0; mt < 4; ++mt)
        #pragma unroll
        for (int reg = 0; reg < 4; ++reg){
          const int row = mt*16 + quad*4 + reg;
          hs[row][col] = f2bf(acc[mt][nt][reg] + bo);   // hs@Vs region: post-barrier(2)
        }
    }
  }
  __syncthreads();   // barrier(3)

  // ---- LayerNorm per row: h = hs + x (coalesced fp32 re-read), fp32 store ----
  {
    #pragma unroll
    for (int rr = 0; rr < 8; ++rr){
      const int r = w*8 + rr;
      const int c = lane*4;
      i32x2 hv2 = *(const i32x2*)&hs[r][c];
      f32x4 xv  = *(const f32x4*)(x + (rowbase + r)*256 + c);
      unsigned int u0 = (unsigned int)hv2[0], u1 = (unsigned int)hv2[1];
      f32x4 hv;
      hv[0] = __builtin_bit_cast(float, u0 << 16)         + xv[0];
      hv[1] = __builtin_bit_cast(float, u0 & 0xFFFF0000u) + xv[1];
      hv[2] = __builtin_bit_cast(float, u1 << 16)         + xv[2];
      hv[3] = __builtin_bit_cast(float, u1 & 0xFFFF0000u) + xv[3];
      float s  = hv[0] + hv[1] + hv[2] + hv[3];
      float s2 = hv[0]*hv[0] + hv[1]*hv[1] + hv[2]*hv[2] + hv[3]*hv[3];
      #pragma unroll
      for (int off = 1; off < 64; off <<= 1){
        s  += __shfl_xor(s,  off);
        s2 += __shfl_xor(s2, off);
      }
      const float mu  = s  * (1.0f/256.0f);
      const float var = s2 * (1.0f/256.0f) - mu*mu;
      const float rs  = rsqrtf(var + 1e-5f);
      f32x4 gv = *(const f32x4*)(gamma + c);
      f32x4 bv = *(const f32x4*)(beta  + c);
      f32x4 y;
      y[0] = (hv[0] - mu)*rs*gv[0] + bv[0];
      y[1] = (hv[1] - mu)*rs*gv[1] + bv[1];
      y[2] = (hv[2] - mu)*rs*gv[2] + bv[2];
      y[3] = (hv[3] - mu)*rs*gv[3] + bv[3];
      *(f32x4*)(out + (rowbase + r)*256 + c) = y;
    }
  }
}

extern "C" void kernel_launch(void* const* d_in, const int* in_sizes, int n_in,
                              void* d_out, int out_size, void* d_ws, size_t ws_size,
                              hipStream_t stream)
{
  const float* x     = (const float*)d_in[0];
  const float* Wq    = (const float*)d_in[1];
  const float* Wk    = (const float*)d_in[2];
  const float* Wv    = (const float*)d_in[3];
  const float* Wout  = (const float*)d_in[4];
  const float* b_out = (const float*)d_in[5];
  const float* L     = (const float*)d_in[6];
  const float* gamma = (const float*)d_in[7];
  const float* beta  = (const float*)d_in[8];
  u16* ws = (u16*)d_ws;

  geo_prep<<<96, 256, 0, stream>>>(Wq, Wk, Wv, Wout, L, ws);
  geo_fused<<<1024, 512, 0, stream>>>(x, ws, ws + 524288, ws + 589824,
                                      b_out, gamma, beta, (float*)d_out);
}

// Round 6
// 266.862 us; speedup vs baseline: 1.1515x; 1.1515x over previous
//
#include <hip/hip_runtime.h>

// GeodesicAttentionBlock fused, fp32 in -> fp32 out, MI355X gfx950.
// R6: algorithmic halving of MFMA work. sq_dist via per-key-head transform:
//   Qt[q,k,f] = L_k^T Q_q (K=32 GEMM, LDS operands), Kt[k,f] = L_k^T K_k,
//   sq = sum_f (Qt-Kt)^2  — replaces the K=256 Wd GEMM (524k -> 203k MACs/row).
// Prep is now transposes only (WqkvT, WoutT, Lt). 32 rows/block, 2048 blocks,
// 67.6KB LDS -> 2 blocks/CU, logits in registers.

typedef __bf16 bf16x8 __attribute__((ext_vector_type(8)));
typedef float  f32x4  __attribute__((ext_vector_type(4)));
typedef int    i32x4  __attribute__((ext_vector_type(4)));
typedef int    i32x2  __attribute__((ext_vector_type(2)));
typedef unsigned short u16;

__device__ __forceinline__ float bf2f(u16 u){
  unsigned int x = ((unsigned int)u) << 16;
  return __builtin_bit_cast(float, x);
}
__device__ __forceinline__ u16 f2bf(float f){
  unsigned int u = __builtin_bit_cast(unsigned int, f);
  u += 0x7FFFu + ((u >> 16) & 1u);          // round-to-nearest-even
  return (u16)(u >> 16);
}
__device__ __forceinline__ unsigned int pk2(float lo, float hi){
  return ((unsigned int)f2bf(hi) << 16) | (unsigned int)f2bf(lo);
}
__device__ __forceinline__ bf16x8 ldfrag_lds(const u16* p){
  return __builtin_bit_cast(bf16x8, *(const i32x4*)p);
}
__device__ __forceinline__ bf16x8 ldfrag_g(const u16* p){
  return __builtin_bit_cast(bf16x8, *(const i32x4*)p);
}

#define LROW 264   // padded bf16 LDS row: 528B stride, 16B-aligned

// ws layout (u16): WqkvT [768][256] @0 ; WoutT [256][256] @196608 ; Lt [8][32][32] @262144
// WqkvT rows: 0-255 = Wq^T, 256-511 = Wk^T, 512-767 = Wv^T.  Lt[k][f][d] = L[k][d][f].
__global__ __launch_bounds__(256) void geo_prep(
    const float* __restrict__ Wq, const float* __restrict__ Wk,
    const float* __restrict__ Wv, const float* __restrict__ Wout,
    const float* __restrict__ L, u16* __restrict__ ws)
{
  const int b = blockIdx.x, t = threadIdx.x;
  if (b < 64){
    const int m = b >> 4;                    // 0=Wq 1=Wk 2=Wv 3=Wout
    const float* src = (m == 0) ? Wq : (m == 1) ? Wk : (m == 2) ? Wv : Wout;
    u16* dstbase = (m < 3) ? (ws + m*65536) : (ws + 196608);
    const int tile = b & 15;
    const int tr = tile >> 2, tc = tile & 3;
    __shared__ float tlf[64][68];
    {
      const int row = t >> 2, cs = (t & 3)*16;
      #pragma unroll
      for (int j = 0; j < 4; ++j){
        f32x4 v = *(const f32x4*)(src + (size_t)(tr*64 + row)*256 + tc*64 + cs + j*4);
        #pragma unroll
        for (int p = 0; p < 4; ++p) tlf[row][cs + j*4 + p] = v[p];
      }
    }
    __syncthreads();
    {
      const int n = t >> 2, cs = (t & 3)*16;
      float us[16];
      #pragma unroll
      for (int j = 0; j < 16; ++j) us[j] = tlf[cs + j][n];
      #pragma unroll
      for (int h = 0; h < 2; ++h){
        i32x4 o;
        #pragma unroll
        for (int p = 0; p < 4; ++p)
          o[p] = (int)pk2(us[h*8 + 2*p], us[h*8 + 2*p + 1]);
        *(i32x4*)(dstbase + (size_t)(tc*64 + n)*256 + tr*64 + cs + h*8) = o;
      }
    }
  } else {
    // Lt: per-head 32x32 transpose of L, fp32 -> bf16
    u16* Lt = ws + 262144;
    const int k = t >> 5, f = t & 31;
    for (int d = 0; d < 32; ++d)
      Lt[k*1024 + f*32 + d] = f2bf(L[k*1024 + d*32 + f]);
  }
}

// LDS regions (67584 B -> 2 blocks/CU):
//   R0 @0     : xs bf16[32][264] -> Kts bf16[8][32][32] after QKV
//   R1 @16896 : Qs bf16[32][264] -> hs  bf16[32][256] in Wout phase
//   R2 @33792 : Ks bf16[32][264] -> ao  bf16[32][264] in attnV phase
//   R3 @50688 : Vs bf16[32][264]
__global__ __launch_bounds__(512, 4) void geo_fused(
    const float* __restrict__ x,     const u16* __restrict__ WqkvT,
    const u16* __restrict__ WoutT,   const u16* __restrict__ Lt,
    const float* __restrict__ b_out, const float* __restrict__ gamma,
    const float* __restrict__ beta,  float* __restrict__ out)
{
  __shared__ __align__(16) char pool[67584];
  u16* xsU  = (u16*)(pool);            // [32][264]
  u16* KtsU = (u16*)(pool);            // [8][32][32] overlays xs
  u16* QsU  = (u16*)(pool + 16896);    // [32][264]
  u16* hsU  = (u16*)(pool + 16896);    // [32][256]  overlays Qs
  u16* KsU  = (u16*)(pool + 33792);    // [32][264]
  u16* aoU  = (u16*)(pool + 33792);    // [32][264]  overlays Ks
  u16* VsU  = (u16*)(pool + 50688);    // [32][264]

  const int t    = threadIdx.x;
  const int lane = t & 63;
  const int w    = t >> 6;             // wave 0..7 == head
  const int l15  = lane & 15;
  const int quad = lane >> 4;
  const long rowbase = (long)blockIdx.x * 32;

  // ---- stage x: 32 rows fp32 -> bf16 LDS ----
  {
    const int r  = t >> 4;
    const int c0 = (t & 15) * 16;
    const float* src = x + (rowbase + r)*256 + c0;
    unsigned int wds[8];
    #pragma unroll
    for (int j = 0; j < 4; ++j){
      f32x4 v = *(const f32x4*)(src + j*4);
      wds[j*2    ] = pk2(v[0], v[1]);
      wds[j*2 + 1] = pk2(v[2], v[3]);
    }
    #pragma unroll
    for (int h = 0; h < 2; ++h){
      i32x4 o;
      #pragma unroll
      for (int p = 0; p < 4; ++p) o[p] = (int)wds[h*4 + p];
      *(i32x4*)&xsU[r*LROW + c0 + h*8] = o;
    }
  }
  __syncthreads();   // b0

  // ---- QKV GEMM: 3 segments (Q,K,V), wave w computes head-w cols of each ----
  #pragma unroll
  for (int s = 0; s < 3; ++s){
    const u16* Bbase = WqkvT + (size_t)(s*256 + w*32)*256;
    u16* dst = (s == 0) ? QsU : (s == 1) ? KsU : VsU;
    f32x4 acc[2][2];
    #pragma unroll
    for (int mt = 0; mt < 2; ++mt)
      #pragma unroll
      for (int nt = 0; nt < 2; ++nt) acc[mt][nt] = f32x4{0.f,0.f,0.f,0.f};
    #pragma unroll
    for (int kk = 0; kk < 8; ++kk){
      const int c0 = kk*32 + quad*8;
      bf16x8 a[2], bb[2];
      #pragma unroll
      for (int mt = 0; mt < 2; ++mt) a[mt] = ldfrag_lds(&xsU[(mt*16 + l15)*LROW + c0]);
      #pragma unroll
      for (int nt = 0; nt < 2; ++nt) bb[nt] = ldfrag_g(Bbase + (size_t)(nt*16 + l15)*256 + c0);
      #pragma unroll
      for (int mt = 0; mt < 2; ++mt)
        #pragma unroll
        for (int nt = 0; nt < 2; ++nt)
          acc[mt][nt] = __builtin_amdgcn_mfma_f32_16x16x32_bf16(a[mt], bb[nt], acc[mt][nt], 0, 0, 0);
    }
    #pragma unroll
    for (int mt = 0; mt < 2; ++mt)
      #pragma unroll
      for (int nt = 0; nt < 2; ++nt){
        const int col = w*32 + nt*16 + l15;
        #pragma unroll
        for (int reg = 0; reg < 4; ++reg)
          dst[(mt*16 + quad*4 + reg)*LROW + col] = f2bf(acc[mt][nt][reg]);
      }
  }
  __syncthreads();   // b1: xs dead; Q,K,V complete

  // ---- Kt: wave w computes Kt[k=w][row][f] = (L_w^T K_w)  -> Kts (overlays xs) ----
  {
    bf16x8 aL[2], bK[2];
    #pragma unroll
    for (int mt = 0; mt < 2; ++mt)
      aL[mt] = ldfrag_g(Lt + w*1024 + (mt*16 + l15)*32 + quad*8);
    #pragma unroll
    for (int nt = 0; nt < 2; ++nt)
      bK[nt] = ldfrag_lds(&KsU[(nt*16 + l15)*LROW + w*32 + quad*8]);
    f32x4 acc[2][2];
    #pragma unroll
    for (int mt = 0; mt < 2; ++mt)
      #pragma unroll
      for (int nt = 0; nt < 2; ++nt)
        acc[mt][nt] = __builtin_amdgcn_mfma_f32_16x16x32_bf16(aL[mt], bK[nt],
                        f32x4{0.f,0.f,0.f,0.f}, 0, 0, 0);
    #pragma unroll
    for (int mt = 0; mt < 2; ++mt)
      #pragma unroll
      for (int nt = 0; nt < 2; ++nt){
        i32x2 o;
        o[0] = (int)pk2(acc[mt][nt][0], acc[mt][nt][1]);
        o[1] = (int)pk2(acc[mt][nt][2], acc[mt][nt][3]);
        *(i32x2*)&KtsU[w*1024 + (nt*16 + l15)*32 + mt*16 + quad*4] = o;
      }
  }
  __syncthreads();   // b2: Kts complete; Ks dead

  // ---- Qt + sq: per k, Qt = L_k^T Q_w; logits to registers ----
  float lg[2][8];
  {
    bf16x8 bQ[2];
    #pragma unroll
    for (int nt = 0; nt < 2; ++nt)
      bQ[nt] = ldfrag_lds(&QsU[(nt*16 + l15)*LROW + w*32 + quad*8]);
    #pragma unroll
    for (int k = 0; k < 8; ++k){
      bf16x8 aL[2];
      #pragma unroll
      for (int mt = 0; mt < 2; ++mt)
        aL[mt] = ldfrag_g(Lt + k*1024 + (mt*16 + l15)*32 + quad*8);
      f32x4 acc[2][2];
      #pragma unroll
      for (int mt = 0; mt < 2; ++mt)
        #pragma unroll
        for (int nt = 0; nt < 2; ++nt)
          acc[mt][nt] = __builtin_amdgcn_mfma_f32_16x16x32_bf16(aL[mt], bQ[nt],
                          f32x4{0.f,0.f,0.f,0.f}, 0, 0, 0);
      #pragma unroll
      for (int nt = 0; nt < 2; ++nt){
        float s = 0.f;
        #pragma unroll
        for (int mt = 0; mt < 2; ++mt){
          i32x2 kt2 = *(const i32x2*)&KtsU[k*1024 + (nt*16 + l15)*32 + mt*16 + quad*4];
          unsigned int u0 = (unsigned int)kt2[0], u1 = (unsigned int)kt2[1];
          float kv0 = __builtin_bit_cast(float, u0 << 16);
          float kv1 = __builtin_bit_cast(float, u0 & 0xFFFF0000u);
          float kv2 = __builtin_bit_cast(float, u1 << 16);
          float kv3 = __builtin_bit_cast(float, u1 & 0xFFFF0000u);
          float d0 = acc[mt][nt][0] - kv0, d1 = acc[mt][nt][1] - kv1;
          float d2 = acc[mt][nt][2] - kv2, d3 = acc[mt][nt][3] - kv3;
          s = fmaf(d0, d0, s); s = fmaf(d1, d1, s);
          s = fmaf(d2, d2, s); s = fmaf(d3, d3, s);
        }
        s += __shfl_xor(s, 16);
        s += __shfl_xor(s, 32);            // all lanes: full sum over 32 f
        lg[nt][k] = s * -0.17677669529663687f;   // -1/sqrt(32)
      }
    }
  }
  __syncthreads();   // b3: Qs dead (hs later), ao may overlay Ks

  // ---- softmax + attn @ V -> ao ----
  {
    #pragma unroll
    for (int nt = 0; nt < 2; ++nt){
      const int r = nt*16 + l15;
      float mx = lg[nt][0];
      #pragma unroll
      for (int k = 1; k < 8; ++k) mx = fmaxf(mx, lg[nt][k]);
      float e[8], sum = 0.f;
      #pragma unroll
      for (int k = 0; k < 8; ++k){ e[k] = __expf(lg[nt][k] - mx); sum += e[k]; }
      const float inv = 1.0f / sum;
      float o[8] = {0.f,0.f,0.f,0.f,0.f,0.f,0.f,0.f};
      #pragma unroll
      for (int k = 0; k < 8; ++k){
        i32x4 v = *(const i32x4*)&VsU[r*LROW + k*32 + quad*8];
        const float a = e[k] * inv;
        #pragma unroll
        for (int p = 0; p < 4; ++p){
          unsigned int u = (unsigned int)v[p];
          o[2*p    ] = fmaf(a, __builtin_bit_cast(float, u << 16),         o[2*p    ]);
          o[2*p + 1] = fmaf(a, __builtin_bit_cast(float, u & 0xFFFF0000u), o[2*p + 1]);
        }
      }
      i32x4 pkv;
      #pragma unroll
      for (int p = 0; p < 4; ++p) pkv[p] = (int)pk2(o[2*p], o[2*p + 1]);
      *(i32x4*)&aoU[r*LROW + w*32 + quad*8] = pkv;
    }
  }
  __syncthreads();   // b4: ao complete

  // ---- Wout GEMM: h' = ao @ Wout + b_out -> hs (overlays Qs) ----
  {
    f32x4 acc[2][2];
    #pragma unroll
    for (int mt = 0; mt < 2; ++mt)
      #pragma unroll
      for (int nt = 0; nt < 2; ++nt) acc[mt][nt] = f32x4{0.f,0.f,0.f,0.f};
    #pragma unroll
    for (int kk = 0; kk < 8; ++kk){
      const int c0 = kk*32 + quad*8;
      bf16x8 a[2], bb[2];
      #pragma unroll
      for (int mt = 0; mt < 2; ++mt) a[mt] = ldfrag_lds(&aoU[(mt*16 + l15)*LROW + c0]);
      #pragma unroll
      for (int nt = 0; nt < 2; ++nt)
        bb[nt] = ldfrag_g(WoutT + (size_t)(w*32 + nt*16 + l15)*256 + c0);
      #pragma unroll
      for (int mt = 0; mt < 2; ++mt)
        #pragma unroll
        for (int nt = 0; nt < 2; ++nt)
          acc[mt][nt] = __builtin_amdgcn_mfma_f32_16x16x32_bf16(a[mt], bb[nt], acc[mt][nt], 0, 0, 0);
    }
    #pragma unroll
    for (int nt = 0; nt < 2; ++nt){
      const int col = w*32 + nt*16 + l15;
      const float bo = b_out[col];
      #pragma unroll
      for (int mt = 0; mt < 2; ++mt)
        #pragma unroll
        for (int reg = 0; reg < 4; ++reg)
          hsU[(mt*16 + quad*4 + reg)*256 + col] = f2bf(acc[mt][nt][reg] + bo);
    }
  }
  __syncthreads();   // b5

  // ---- LayerNorm: h = hs + x (fp32 re-read), fp32 store ----
  {
    #pragma unroll
    for (int rr = 0; rr < 4; ++rr){
      const int r = w*4 + rr;
      const int c = lane*4;
      i32x2 h2 = *(const i32x2*)&hsU[r*256 + c];
      f32x4 xv = *(const f32x4*)(x + (rowbase + r)*256 + c);
      unsigned int u0 = (unsigned int)h2[0], u1 = (unsigned int)h2[1];
      f32x4 hv;
      hv[0] = __builtin_bit_cast(float, u0 << 16)         + xv[0];
      hv[1] = __builtin_bit_cast(float, u0 & 0xFFFF0000u) + xv[1];
      hv[2] = __builtin_bit_cast(float, u1 << 16)         + xv[2];
      hv[3] = __builtin_bit_cast(float, u1 & 0xFFFF0000u) + xv[3];
      float s  = hv[0] + hv[1] + hv[2] + hv[3];
      float s2 = hv[0]*hv[0] + hv[1]*hv[1] + hv[2]*hv[2] + hv[3]*hv[3];
      #pragma unroll
      for (int off = 1; off < 64; off <<= 1){
        s  += __shfl_xor(s,  off);
        s2 += __shfl_xor(s2, off);
      }
      const float mu  = s  * (1.0f/256.0f);
      const float var = s2 * (1.0f/256.0f) - mu*mu;
      const float rs  = rsqrtf(var + 1e-5f);
      f32x4 gv = *(const f32x4*)(gamma + c);
      f32x4 bv = *(const f32x4*)(beta  + c);
      f32x4 y;
      y[0] = (hv[0] - mu)*rs*gv[0] + bv[0];
      y[1] = (hv[1] - mu)*rs*gv[1] + bv[1];
      y[2] = (hv[2] - mu)*rs*gv[2] + bv[2];
      y[3] = (hv[3] - mu)*rs*gv[3] + bv[3];
      *(f32x4*)(out + (rowbase + r)*256 + c) = y;
    }
  }
}

extern "C" void kernel_launch(void* const* d_in, const int* in_sizes, int n_in,
                              void* d_out, int out_size, void* d_ws, size_t ws_size,
                              hipStream_t stream)
{
  const float* x     = (const float*)d_in[0];
  const float* Wq    = (const float*)d_in[1];
  const float* Wk    = (const float*)d_in[2];
  const float* Wv    = (const float*)d_in[3];
  const float* Wout  = (const float*)d_in[4];
  const float* b_out = (const float*)d_in[5];
  const float* L     = (const float*)d_in[6];
  const float* gamma = (const float*)d_in[7];
  const float* beta  = (const float*)d_in[8];
  u16* ws = (u16*)d_ws;

  geo_prep<<<65, 256, 0, stream>>>(Wq, Wk, Wv, Wout, L, ws);
  geo_fused<<<2048, 512, 0, stream>>>(x, ws, ws + 196608, ws + 262144,
                                      b_out, gamma, beta, (float*)d_out);
}